// Round 12
// baseline (25.559 us; speedup 1.0000x reference)
//
#include <hip/hip_runtime.h>

// ---------------- types / helpers ----------------
typedef short bf16x8 __attribute__((ext_vector_type(8)));
typedef float f32x4  __attribute__((ext_vector_type(4)));

// ws layout (floats): [0,30720) = Apack (61440 bf16 = 20 ksteps * 6144 B)
//                     [30720,30816) = cst96, [30816,30822) = qbias
#define WS_CONST 30720
#define WS_QBIAS 30816

__device__ __forceinline__ short f2bf(float f) {
    unsigned u = __float_as_uint(f);
    unsigned r = (u + 0x7FFFu + ((u >> 16) & 1u)) >> 16;  // RNE
    return (short)r;
}

// ---------------- prep (R9 version, unchanged) ----------------
__global__ __launch_bounds__(256) void prep_kernel(
    const float* __restrict__ W_query, const float* __restrict__ b_query,
    const float* __restrict__ W_x,     const float* __restrict__ b_x,
    const float* __restrict__ W_ret0,  const float* __restrict__ b_ret0,
    const float* __restrict__ W_ret1,  const float* __restrict__ b_ret1,
    const float* __restrict__ W_ret2,  const float* __restrict__ b_ret2,
    const float* __restrict__ W_pred,  const float* __restrict__ b_pred,
    const float* __restrict__ angles,  const int* __restrict__ wires,
    float* __restrict__ ws)
{
    const int bid = blockIdx.x;
    const int t = threadIdx.x;
    __shared__ float wp[3072];   // W_pred slab [32 rows][96 k]
    __shared__ float wsl[768];   // slice [96 k][8 s]
    short* ap = (short*)ws;

    if (bid < 240) {
        const int rg = bid % 3;              // row group (32 rows)
        const int cg = bid / 3;              // col group (8 cols); <64 = M1, else M2
        const bool isM1 = cg < 64;
        const int off = isM1 ? 0 : 96;
        #pragma unroll
        for (int i = 0; i < 12; ++i) {
            int L = t + i * 256;             // 0..3071
            int r = L / 96, k = L - r * 96;
            wp[L] = W_pred[(rg * 32 + r) * 192 + off + k];
        }
        if (isM1) {
            const int s0 = cg * 8;
            #pragma unroll
            for (int i = 0; i < 3; ++i) {
                int L = t + i * 256;
                int k = L >> 3, s = L & 7;
                wsl[L] = W_x[k * 512 + s0 + s];
            }
        } else {
            const int j0 = (cg - 64) * 8;
            #pragma unroll
            for (int i = 0; i < 3; ++i) {
                int L = t + i * 256;
                int k = L >> 3, jj = L & 7;
                int j = j0 + jj;
                float v = 0.f;
                if (j < 104) {
                    const float* Wr; int d, jl;
                    if (j < 48)      { Wr = W_ret0; d = 48; jl = j; }
                    else if (j < 80) { Wr = W_ret1; d = 32; jl = j - 48; }
                    else             { Wr = W_ret2; d = 24; jl = j - 80; }
                    v = Wr[k * d + jl];
                }
                wsl[L] = v;
            }
        }
        __syncthreads();
        const int rl = t >> 3, s = t & 7;
        float acc = 0.f;
        #pragma unroll 8
        for (int k = 0; k < 96; ++k) acc += wp[rl * 96 + k] * wsl[k * 8 + s];
        const int r = rg * 32 + rl;
        const int sg = isM1 ? (cg * 8 + s) : (512 + (cg - 64) * 8 + s);
        const int kstep = sg >> 5, s32 = sg & 31;
        const int g = s32 >> 3, e = s32 & 7;
        ap[kstep * 3072 + (r >> 4) * 512 + (g * 16 + (r & 15)) * 8 + e] = f2bf(acc);
    } else {
        if (t < 96) {
            float v = b_pred[t];
            for (int k = 0; k < 96; ++k) {
                v += W_pred[t * 192 + k] * b_x[k];
                v += W_pred[t * 192 + 96 + k] * (b_ret0[k] + b_ret1[k] + b_ret2[k]);
            }
            ws[WS_CONST + t] = v;
        } else if (t < 102) {
            int w = t - 96;
            float v = b_query[w];
            for (int k = 0; k < 18; ++k)
                if (wires[k] == w) v += angles[k];
            ws[WS_QBIAS + w] = v;
        }
    }
}

// ---------------- main kernel: float4 x-pass + in-register q reduce ----------------
// grid 512: b = bid&127, c-quarter = bid>>7 (16 cols). 512 threads = 8 waves.
// vs R11: x loaded as float4 (thread (c4,sg) owns rows sg*4..+3, cols c4*4..+3;
// 4x fewer VMEM instructions), q partials reduced in-register via shfl_xor over
// the 16 sg-groups per wave (LDS partial buffer 12KB -> 3KB). Rest identical.
__global__ __launch_bounds__(512) void main_kernel(
    const float* __restrict__ x_enc,
    const int*   __restrict__ index,
    const float* __restrict__ W_query,
    const float* __restrict__ W_prob,
    const float* __restrict__ b_prob,
    const float* __restrict__ RT,
    const float* __restrict__ gumbel,
    const float* __restrict__ ws,
    float* __restrict__ out)
{
    const int bid = blockIdx.x;
    const int b = bid & 127;
    const int cbase = (bid >> 7) * 16;
    const int t = threadIdx.x;
    const int lane = t & 63;
    const int wv = t >> 6;
    const int cl = lane & 15, g = lane >> 4;

    __shared__ __align__(16) union {
        float qp2[768];                      // [wave 8][w 6][c 16] q wave-partials
        short selbuf[16][136];               // [c][j 128+pad] bf16
    } u0;
    __shared__ __align__(16) short xbuf[16][520];   // [c][k 512] bf16
    __shared__ float qfin[96];               // [w6][16]
    __shared__ int m_sel[16];

    const float* __restrict__ xb = x_enc + (size_t)b * 32768;

    // ---- x pass: thread (c4 = t&3, sg = t>>2) loads rows sg*4..+3, cols c4*4..+3 ----
    const int c4 = t & 3;
    const int sg = t >> 2;                   // 0..127
    float4 xo4 = *(const float4*)(xb + 511 * 64 + cbase + c4 * 4);
    float4 v4[4];
    #pragma unroll
    for (int i = 0; i < 4; ++i)
        v4[i] = *(const float4*)(xb + (size_t)(sg * 4 + i) * 64 + cbase + c4 * 4);
    #pragma unroll
    for (int i = 0; i < 4; ++i) {
        v4[i].x -= xo4.x; v4[i].y -= xo4.y; v4[i].z -= xo4.z; v4[i].w -= xo4.w;
    }

    // ---- fp32 q partials, in-register wave reduce ----
    {
        float4 pw[6];
        #pragma unroll
        for (int w = 0; w < 6; ++w) {
            pw[w].x = pw[w].y = pw[w].z = pw[w].w = 0.f;
            #pragma unroll
            for (int i = 0; i < 4; ++i) {
                float s = W_query[w * 512 + sg * 4 + i];
                pw[w].x += s * v4[i].x; pw[w].y += s * v4[i].y;
                pw[w].z += s * v4[i].z; pw[w].w += s * v4[i].w;
            }
        }
        // reduce over the wave's 16 sg-groups (lane bits 2..5)
        #pragma unroll
        for (int mask = 4; mask <= 32; mask <<= 1) {
            #pragma unroll
            for (int w = 0; w < 6; ++w) {
                pw[w].x += __shfl_xor(pw[w].x, mask);
                pw[w].y += __shfl_xor(pw[w].y, mask);
                pw[w].z += __shfl_xor(pw[w].z, mask);
                pw[w].w += __shfl_xor(pw[w].w, mask);
            }
        }
        if ((lane & 60) == 0) {              // one writer per c4 group (lanes 0..3)
            #pragma unroll
            for (int w = 0; w < 6; ++w) {
                u0.qp2[wv * 96 + w * 16 + c4 * 4 + 0] = pw[w].x;
                u0.qp2[wv * 96 + w * 16 + c4 * 4 + 1] = pw[w].y;
                u0.qp2[wv * 96 + w * 16 + c4 * 4 + 2] = pw[w].z;
                u0.qp2[wv * 96 + w * 16 + c4 * 4 + 3] = pw[w].w;
            }
        }
        // bf16 xbuf writes: 4 cols x 4 rows -> 2x u32 per col
        #pragma unroll
        for (int j = 0; j < 4; ++j) {
            const int cc = c4 * 4 + j;
            const float vj0 = j == 0 ? v4[0].x : j == 1 ? v4[0].y : j == 2 ? v4[0].z : v4[0].w;
            const float vj1 = j == 0 ? v4[1].x : j == 1 ? v4[1].y : j == 2 ? v4[1].z : v4[1].w;
            const float vj2 = j == 0 ? v4[2].x : j == 1 ? v4[2].y : j == 2 ? v4[2].z : v4[2].w;
            const float vj3 = j == 0 ? v4[3].x : j == 1 ? v4[3].y : j == 2 ? v4[3].z : v4[3].w;
            unsigned p0 = (unsigned short)f2bf(vj0) | ((unsigned)(unsigned short)f2bf(vj1) << 16);
            unsigned p1 = (unsigned short)f2bf(vj2) | ((unsigned)(unsigned short)f2bf(vj3) << 16);
            uint2 pk; pk.x = p0; pk.y = p1;
            *(uint2*)&xbuf[cc][sg * 4] = pk;
        }
    }
    __syncthreads();   // B1: qp2, xbuf ready

    // q reduce over 8 waves
    if (t < 96) {
        int w6 = t >> 4, cc = t & 15;
        float s = 0.f;
        #pragma unroll
        for (int w2 = 0; w2 < 8; ++w2) s += u0.qp2[w2 * 96 + w6 * 16 + cc];
        qfin[w6 * 16 + cc] = s;
    }
    __syncthreads();   // B2: qfin ready, qp2 dead

    // argmax (fp32 q path)
    if (t < 16) {
        float e[6];
        #pragma unroll
        for (int w = 0; w < 6; ++w) e[w] = cosf(qfin[w * 16 + t] + ws[WS_QBIAS + w]);
        int grow = (b * 64 + cbase + t) * 4;
        float best = -1e30f; int bm = 0;
        #pragma unroll
        for (int m = 0; m < 4; ++m) {
            float lg = b_prob[m];
            #pragma unroll
            for (int w = 0; w < 6; ++w) lg += W_prob[m * 6 + w] * e[w];
            lg += gumbel[grow + m];          // argmax invariant under /0.5
            if (lg > best) { best = lg; bm = m; }   // first-max like jnp.argmax
        }
        m_sel[t] = bm;
    }
    __syncthreads();   // B3: m_sel ready; qp2 region reusable as selbuf

    // issue RT gather into registers (latency hides under x-MFMA below)
    const int idxb = index[b];
    float gv[5];
    #pragma unroll
    for (int it = 0; it < 5; ++it) {
        const int L = t + it * 512;
        float val = 0.f;
        if (L < 2176) {
            const int cc = L & 15, j = L >> 4;
            if (j < 104) {
                int i, row;
                if (j < 48)      { i = 0; row = j * 2; }
                else if (j < 80) { i = 1; row = (j - 48) * 3; }
                else             { i = 2; row = (j - 80) * 4; }
                val = RT[(size_t)i * 122880000ull + (size_t)idxb * 24576ull
                         + (size_t)m_sel[cc] * 6144ull + (size_t)row * 64ull + cbase + cc];
            }
        }
        gv[it] = val;
    }

    // x-part MFMA: 16 ksteps, A direct global->VGPR (coalesced, L2-hot, per-wave slice)
    const char* Ap = (const char*)ws;
    f32x4 acc = {0,0,0,0};
    if (wv < 6) {
        #pragma unroll 4
        for (int ks = 0; ks < 16; ++ks) {
            bf16x8 av = *(const bf16x8*)(Ap + ks * 6144 + wv * 1024 + lane * 16);
            bf16x8 bv = *(const bf16x8*)&xbuf[cl][ks * 32 + g * 8];
            acc = __builtin_amdgcn_mfma_f32_16x16x32_bf16(av, bv, acc, 0, 0, 0);
        }
    }

    // write gathered values to selbuf (bf16; j>=104 pads write 0)
    #pragma unroll
    for (int it = 0; it < 5; ++it) {
        const int L = t + it * 512;
        if (L < 2176) {
            const int cc = L & 15, j = L >> 4;
            u0.selbuf[cc][j] = f2bf(gv[it]);
        }
    }
    __syncthreads();   // B4: selbuf ready

    // sel-part MFMA + epilogue
    if (wv < 6) {
        #pragma unroll
        for (int ks = 0; ks < 4; ++ks) {
            bf16x8 av = *(const bf16x8*)(Ap + (16 + ks) * 6144 + wv * 1024 + lane * 16);
            bf16x8 bv = *(const bf16x8*)&u0.selbuf[cl][ks * 32 + g * 8];
            acc = __builtin_amdgcn_mfma_f32_16x16x32_bf16(av, bv, acc, 0, 0, 0);
        }
        // epilogue: D layout col=lane&15, row=4*(lane>>4)+reg (m89-verified)
        const float* cst = ws + WS_CONST;
        float xo0 = xb[511 * 64 + cbase + cl];
        int r0 = wv * 16 + g * 4;
        float* op = out + (size_t)b * 6144 + (size_t)r0 * 64 + cbase;
        #pragma unroll
        for (int reg = 0; reg < 4; ++reg)
            op[reg * 64 + cl] = acc[reg] + cst[r0 + reg] + xo0;
    }
}

extern "C" void kernel_launch(void* const* d_in, const int* in_sizes, int n_in,
                              void* d_out, int out_size, void* d_ws, size_t ws_size,
                              hipStream_t stream) {
    (void)in_sizes; (void)n_in; (void)out_size; (void)ws_size;
    const float* x_enc   = (const float*)d_in[0];
    const int*   index   = (const int*)d_in[1];
    const float* W_query = (const float*)d_in[2];
    const float* b_query = (const float*)d_in[3];
    const float* W_x     = (const float*)d_in[4];
    const float* b_x     = (const float*)d_in[5];
    const float* W_prob  = (const float*)d_in[6];
    const float* b_prob  = (const float*)d_in[7];
    const float* W_ret0  = (const float*)d_in[8];
    const float* b_ret0  = (const float*)d_in[9];
    const float* W_ret1  = (const float*)d_in[10];
    const float* b_ret1  = (const float*)d_in[11];
    const float* W_ret2  = (const float*)d_in[12];
    const float* b_ret2  = (const float*)d_in[13];
    const float* W_pred  = (const float*)d_in[14];
    const float* b_pred  = (const float*)d_in[15];
    const float* RT      = (const float*)d_in[16];
    const float* angles  = (const float*)d_in[17];
    const int*   wires   = (const int*)d_in[18];
    const float* gumbel  = (const float*)d_in[19];
    float* out = (float*)d_out;
    float* ws  = (float*)d_ws;

    prep_kernel<<<241, 256, 0, stream>>>(W_query, b_query, W_x, b_x,
                                         W_ret0, b_ret0, W_ret1, b_ret1, W_ret2, b_ret2,
                                         W_pred, b_pred, angles, wires, ws);
    main_kernel<<<512, 512, 0, stream>>>(x_enc, index, W_query, W_prob, b_prob,
                                         RT, gumbel, ws, out);
}

// Round 13
// 23.263 us; speedup vs baseline: 1.0987x; 1.0987x over previous
//
#include <hip/hip_runtime.h>

// ---------------- types / helpers ----------------
typedef short bf16x8 __attribute__((ext_vector_type(8)));
typedef float f32x4  __attribute__((ext_vector_type(4)));

// ws layout (floats): [0,30720) = Apack (61440 bf16 = 20 ksteps * 6144 B)
//                     [30720,30816) = cst96, [30816,30822) = qbias
#define WS_CONST 30720
#define WS_QBIAS 30816

__device__ __forceinline__ short f2bf(float f) {
    unsigned u = __float_as_uint(f);
    unsigned r = (u + 0x7FFFu + ((u >> 16) & 1u)) >> 16;  // RNE
    return (short)r;
}

// ---------------- prep (R9 version, unchanged) ----------------
__global__ __launch_bounds__(256) void prep_kernel(
    const float* __restrict__ W_query, const float* __restrict__ b_query,
    const float* __restrict__ W_x,     const float* __restrict__ b_x,
    const float* __restrict__ W_ret0,  const float* __restrict__ b_ret0,
    const float* __restrict__ W_ret1,  const float* __restrict__ b_ret1,
    const float* __restrict__ W_ret2,  const float* __restrict__ b_ret2,
    const float* __restrict__ W_pred,  const float* __restrict__ b_pred,
    const float* __restrict__ angles,  const int* __restrict__ wires,
    float* __restrict__ ws)
{
    const int bid = blockIdx.x;
    const int t = threadIdx.x;
    __shared__ float wp[3072];   // W_pred slab [32 rows][96 k]
    __shared__ float wsl[768];   // slice [96 k][8 s]
    short* ap = (short*)ws;

    if (bid < 240) {
        const int rg = bid % 3;              // row group (32 rows)
        const int cg = bid / 3;              // col group (8 cols); <64 = M1, else M2
        const bool isM1 = cg < 64;
        const int off = isM1 ? 0 : 96;
        #pragma unroll
        for (int i = 0; i < 12; ++i) {
            int L = t + i * 256;             // 0..3071
            int r = L / 96, k = L - r * 96;
            wp[L] = W_pred[(rg * 32 + r) * 192 + off + k];
        }
        if (isM1) {
            const int s0 = cg * 8;
            #pragma unroll
            for (int i = 0; i < 3; ++i) {
                int L = t + i * 256;
                int k = L >> 3, s = L & 7;
                wsl[L] = W_x[k * 512 + s0 + s];
            }
        } else {
            const int j0 = (cg - 64) * 8;
            #pragma unroll
            for (int i = 0; i < 3; ++i) {
                int L = t + i * 256;
                int k = L >> 3, jj = L & 7;
                int j = j0 + jj;
                float v = 0.f;
                if (j < 104) {
                    const float* Wr; int d, jl;
                    if (j < 48)      { Wr = W_ret0; d = 48; jl = j; }
                    else if (j < 80) { Wr = W_ret1; d = 32; jl = j - 48; }
                    else             { Wr = W_ret2; d = 24; jl = j - 80; }
                    v = Wr[k * d + jl];
                }
                wsl[L] = v;
            }
        }
        __syncthreads();
        const int rl = t >> 3, s = t & 7;
        float acc = 0.f;
        #pragma unroll 8
        for (int k = 0; k < 96; ++k) acc += wp[rl * 96 + k] * wsl[k * 8 + s];
        const int r = rg * 32 + rl;
        const int sg = isM1 ? (cg * 8 + s) : (512 + (cg - 64) * 8 + s);
        const int kstep = sg >> 5, s32 = sg & 31;
        const int g = s32 >> 3, e = s32 & 7;
        ap[kstep * 3072 + (r >> 4) * 512 + (g * 16 + (r & 15)) * 8 + e] = f2bf(acc);
    } else {
        if (t < 96) {
            float v = b_pred[t];
            for (int k = 0; k < 96; ++k) {
                v += W_pred[t * 192 + k] * b_x[k];
                v += W_pred[t * 192 + 96 + k] * (b_ret0[k] + b_ret1[k] + b_ret2[k]);
            }
            ws[WS_CONST + t] = v;
        } else if (t < 102) {
            int w = t - 96;
            float v = b_query[w];
            for (int k = 0; k < 18; ++k)
                if (wires[k] == w) v += angles[k];
            ws[WS_QBIAS + w] = v;
        }
    }
}

// ---------------- main kernel: 4-barrier structure (R11 verified, 23.32 us) ----------------
// grid 512: b = bid&127, c-quarter = bid>>7 (16 cols). 512 threads = 8 waves.
//  - W_query read direct from global (L2-hot), no staging barrier
//  - Apack read direct global->VGPR per kstep (per-wave private slice)
//  - RT gather issued into registers before x-MFMA, written to LDS after
__global__ __launch_bounds__(512) void main_kernel(
    const float* __restrict__ x_enc,
    const int*   __restrict__ index,
    const float* __restrict__ W_query,
    const float* __restrict__ W_prob,
    const float* __restrict__ b_prob,
    const float* __restrict__ RT,
    const float* __restrict__ gumbel,
    const float* __restrict__ ws,
    float* __restrict__ out)
{
    const int bid = blockIdx.x;
    const int b = bid & 127;
    const int cbase = (bid >> 7) * 16;
    const int t = threadIdx.x;
    const int lane = t & 63;
    const int wv = t >> 6;
    const int cl = lane & 15, g = lane >> 4;

    __shared__ __align__(16) union {
        float qp[3072];                      // [32 sg][6 w][16 c] q partials
        short selbuf[16][136];               // [c][j 128+pad] bf16
    } u0;
    __shared__ __align__(16) short xbuf[16][520];   // [c][k 512] bf16
    __shared__ float qfin[96];               // [w6][16]
    __shared__ int m_sel[16];

    const float* __restrict__ xb = x_enc + (size_t)b * 32768;

    // single x pass: thread (c 0..15, sg 0..31) loads 16 rows at column c
    const int c  = t & 15;
    const int sg = t >> 4;
    const float xo = xb[511 * 64 + cbase + c];
    const float* xs = xb + (size_t)(sg * 16) * 64 + cbase + c;
    float v[16];
    #pragma unroll
    for (int i = 0; i < 16; ++i) v[i] = xs[i * 64];

    // fp32 q partials (W_query direct from global, same values/order as staged)
    {
        #pragma unroll
        for (int i = 0; i < 16; ++i) v[i] -= xo;
        const float4* wq4 = (const float4*)W_query;      // [6][128] float4 view
        #pragma unroll
        for (int wr = 0; wr < 6; ++wr) {
            float a = 0.f;
            #pragma unroll
            for (int i4 = 0; i4 < 4; ++i4) {
                float4 w4 = wq4[wr * 128 + sg * 4 + i4]; // uniform per 16-lane group
                a += w4.x * v[i4*4+0] + w4.y * v[i4*4+1] + w4.z * v[i4*4+2] + w4.w * v[i4*4+3];
            }
            u0.qp[sg * 96 + wr * 16 + c] = a;
        }
        short* xrow = &xbuf[c][sg * 16];
        #pragma unroll
        for (int i = 0; i < 16; i += 2) {
            unsigned lo = (unsigned short)f2bf(v[i]);
            unsigned hi = (unsigned short)f2bf(v[i+1]);
            *(unsigned*)&xrow[i] = lo | (hi << 16);
        }
    }
    __syncthreads();   // B1: qp, xbuf ready

    // q reduce over 32 sg-groups
    if (t < 96) {
        int w6 = t >> 4, cc = t & 15;
        const float* qp = u0.qp;
        float s = 0.f;
        #pragma unroll
        for (int g2 = 0; g2 < 32; ++g2) s += qp[g2 * 96 + w6 * 16 + cc];
        qfin[w6 * 16 + cc] = s;
    }
    __syncthreads();   // B2: qfin ready, qp dead

    // argmax (fp32 q path)
    if (t < 16) {
        float e[6];
        #pragma unroll
        for (int w = 0; w < 6; ++w) e[w] = cosf(qfin[w * 16 + t] + ws[WS_QBIAS + w]);
        int grow = (b * 64 + cbase + t) * 4;
        float best = -1e30f; int bm = 0;
        #pragma unroll
        for (int m = 0; m < 4; ++m) {
            float lg = b_prob[m];
            #pragma unroll
            for (int w = 0; w < 6; ++w) lg += W_prob[m * 6 + w] * e[w];
            lg += gumbel[grow + m];          // argmax invariant under /0.5
            if (lg > best) { best = lg; bm = m; }   // first-max like jnp.argmax
        }
        m_sel[t] = bm;
    }
    __syncthreads();   // B3: m_sel ready; qp region reusable as selbuf

    // issue RT gather into registers (latency hides under x-MFMA below)
    const int idxb = index[b];
    float gv[5];
    #pragma unroll
    for (int it = 0; it < 5; ++it) {
        const int L = t + it * 512;
        float val = 0.f;
        if (L < 2176) {
            const int cc = L & 15, j = L >> 4;
            if (j < 104) {
                int i, row;
                if (j < 48)      { i = 0; row = j * 2; }
                else if (j < 80) { i = 1; row = (j - 48) * 3; }
                else             { i = 2; row = (j - 80) * 4; }
                val = RT[(size_t)i * 122880000ull + (size_t)idxb * 24576ull
                         + (size_t)m_sel[cc] * 6144ull + (size_t)row * 64ull + cbase + cc];
            }
        }
        gv[it] = val;
    }

    // x-part MFMA: 16 ksteps, A direct global->VGPR (coalesced, L2-hot, per-wave slice)
    const char* Ap = (const char*)ws;
    f32x4 acc = {0,0,0,0};
    if (wv < 6) {
        #pragma unroll 4
        for (int ks = 0; ks < 16; ++ks) {
            bf16x8 av = *(const bf16x8*)(Ap + ks * 6144 + wv * 1024 + lane * 16);
            bf16x8 bv = *(const bf16x8*)&xbuf[cl][ks * 32 + g * 8];
            acc = __builtin_amdgcn_mfma_f32_16x16x32_bf16(av, bv, acc, 0, 0, 0);
        }
    }

    // write gathered values to selbuf (bf16; j>=104 pads write 0)
    #pragma unroll
    for (int it = 0; it < 5; ++it) {
        const int L = t + it * 512;
        if (L < 2176) {
            const int cc = L & 15, j = L >> 4;
            u0.selbuf[cc][j] = f2bf(gv[it]);
        }
    }
    __syncthreads();   // B4: selbuf ready

    // sel-part MFMA + epilogue
    if (wv < 6) {
        #pragma unroll
        for (int ks = 0; ks < 4; ++ks) {
            bf16x8 av = *(const bf16x8*)(Ap + (16 + ks) * 6144 + wv * 1024 + lane * 16);
            bf16x8 bv = *(const bf16x8*)&u0.selbuf[cl][ks * 32 + g * 8];
            acc = __builtin_amdgcn_mfma_f32_16x16x32_bf16(av, bv, acc, 0, 0, 0);
        }
        // epilogue: D layout col=lane&15, row=4*(lane>>4)+reg (m89-verified)
        const float* cst = ws + WS_CONST;
        float xo0 = xb[511 * 64 + cbase + cl];
        int r0 = wv * 16 + g * 4;
        float* op = out + (size_t)b * 6144 + (size_t)r0 * 64 + cbase;
        #pragma unroll
        for (int reg = 0; reg < 4; ++reg)
            op[reg * 64 + cl] = acc[reg] + cst[r0 + reg] + xo0;
    }
}

extern "C" void kernel_launch(void* const* d_in, const int* in_sizes, int n_in,
                              void* d_out, int out_size, void* d_ws, size_t ws_size,
                              hipStream_t stream) {
    (void)in_sizes; (void)n_in; (void)out_size; (void)ws_size;
    const float* x_enc   = (const float*)d_in[0];
    const int*   index   = (const int*)d_in[1];
    const float* W_query = (const float*)d_in[2];
    const float* b_query = (const float*)d_in[3];
    const float* W_x     = (const float*)d_in[4];
    const float* b_x     = (const float*)d_in[5];
    const float* W_prob  = (const float*)d_in[6];
    const float* b_prob  = (const float*)d_in[7];
    const float* W_ret0  = (const float*)d_in[8];
    const float* b_ret0  = (const float*)d_in[9];
    const float* W_ret1  = (const float*)d_in[10];
    const float* b_ret1  = (const float*)d_in[11];
    const float* W_ret2  = (const float*)d_in[12];
    const float* b_ret2  = (const float*)d_in[13];
    const float* W_pred  = (const float*)d_in[14];
    const float* b_pred  = (const float*)d_in[15];
    const float* RT      = (const float*)d_in[16];
    const float* angles  = (const float*)d_in[17];
    const int*   wires   = (const int*)d_in[18];
    const float* gumbel  = (const float*)d_in[19];
    float* out = (float*)d_out;
    float* ws  = (float*)d_ws;

    prep_kernel<<<241, 256, 0, stream>>>(W_query, b_query, W_x, b_x,
                                         W_ret0, b_ret0, W_ret1, b_ret1, W_ret2, b_ret2,
                                         W_pred, b_pred, angles, wires, ws);
    main_kernel<<<512, 512, 0, stream>>>(x_enc, index, W_query, W_prob, b_prob,
                                         RT, gumbel, ws, out);
}